// Round 16
// baseline (174.320 us; speedup 1.0000x reference)
//
#include <hip/hip_runtime.h>

#define LOG2E 1.4426950408889634f
#define NEGBIG -3.0e38f

typedef float  f32x4  __attribute__((ext_vector_type(4)));
typedef float  f32x16 __attribute__((ext_vector_type(16)));
typedef short  bf16x8 __attribute__((ext_vector_type(8)));
typedef unsigned short u16x4 __attribute__((ext_vector_type(4)));
typedef int    i32x4  __attribute__((ext_vector_type(4)));
typedef unsigned int u32x2 __attribute__((ext_vector_type(2)));

__device__ __forceinline__ unsigned short f2bf(float f) {
  union { float f; unsigned u; } v; v.f = f;
  unsigned r = v.u + 0x7FFFu + ((v.u >> 16) & 1u);
  return (unsigned short)(r >> 16);
}

__device__ __forceinline__ unsigned cvtpk(float a, float b) {
  unsigned r;
  asm("v_cvt_pk_bf16_f32 %0, %1, %2" : "=v"(r) : "v"(a), "v"(b));
  return r;
}

__device__ __forceinline__ bf16x8 load_cvt8(const float* p) {
  f32x4 a = *(const f32x4*)p;
  f32x4 b = *(const f32x4*)(p + 4);
  bf16x8 r;
  r[0]=(short)f2bf(a[0]); r[1]=(short)f2bf(a[1]); r[2]=(short)f2bf(a[2]); r[3]=(short)f2bf(a[3]);
  r[4]=(short)f2bf(b[0]); r[5]=(short)f2bf(b[1]); r[6]=(short)f2bf(b[2]); r[7]=(short)f2bf(b[3]);
  return r;
}

// ---------------------------------------------------------------------------
// Kernel 1: QKV projection + weight repack (R15 version, known-good).
// mode 0: Q linear; mode 1: K fragment order; mode 2: V fragment order;
// mode 3: wo -> woF bf16 fragment order.
// ---------------------------------------------------------------------------
__global__ __launch_bounds__(256) void qkv_kernel(
    const float* __restrict__ x,
    const float* __restrict__ wq, const float* __restrict__ wk, const float* __restrict__ wv,
    const float* __restrict__ wo,
    unsigned short* __restrict__ Qo, unsigned short* __restrict__ Ko,
    unsigned short* __restrict__ Vto, unsigned short* __restrict__ woF)
{
  const int mode = blockIdx.y;
  if (mode == 3) {
    const int e = (blockIdx.x*256 + threadIdx.x) * 2;   // 0..65534, even
    const int wv_ = e >> 13;
    const int ks  = (e >> 10) & 7;
    const int df  = (e >> 9) & 1;
    const int lp  = (e >> 3) & 63;
    const int j   = e & 7;
    const int row = wv_*32 + df*16 + (lp & 15);
    const int col = ks*32 + (lp >> 4)*8 + j;
    const float a0 = wo[(size_t)row*256 + col];
    const float a1 = wo[(size_t)row*256 + col + 1];
    woF[e]     = f2bf(a0);
    woF[e + 1] = f2bf(a1);
    return;
  }
  const int n0   = blockIdx.x * 64;
  const int b    = n0 >> 11;
  const int nl0  = n0 & 2047;
  const int wave = threadIdx.x >> 6;
  const int lane = threadIdx.x & 63;
  const int li = lane & 15, qt = lane >> 4;

  f32x4 acc[4][4];
#pragma unroll
  for (int i = 0; i < 4; i++)
#pragma unroll
    for (int j = 0; j < 4; j++) acc[i][j] = (f32x4)0.0f;

  if (mode < 2) {
    const float* w = mode ? wk : wq;
    const float osc = mode ? 1.0f : (1.4426950408889634f / 5.656854249492381f);
#pragma unroll
    for (int ks = 0; ks < 8; ks++) {
      bf16x8 af[4], bfr[4];
#pragma unroll
      for (int dm = 0; dm < 4; dm++)
        af[dm] = load_cvt8(w + (size_t)(wave*64 + dm*16 + li)*256 + ks*32 + qt*8);
#pragma unroll
      for (int nf = 0; nf < 4; nf++)
        bfr[nf] = load_cvt8(x + (size_t)(n0 + nf*16 + li)*256 + ks*32 + qt*8);
#pragma unroll
      for (int dm = 0; dm < 4; dm++)
#pragma unroll
        for (int nf = 0; nf < 4; nf++)
          acc[dm][nf] = __builtin_amdgcn_mfma_f32_16x16x32_bf16(af[dm], bfr[nf], acc[dm][nf], 0, 0, 0);
    }
#pragma unroll
    for (int dm = 0; dm < 4; dm++) {
      const int dbase = wave*64 + dm*16 + qt*4;
      const int h = dbase >> 5, dk = dbase & 31;
#pragma unroll
      for (int nf = 0; nf < 4; nf++) {
        const int nl = nl0 + nf*16 + li;
        u16x4 o;
#pragma unroll
        for (int r = 0; r < 4; r++) o[r] = f2bf(acc[dm][nf][r] * osc);
        if (mode == 0) {
          *(u16x4*)(Qo + ((size_t)(b*8 + h)*2048 + nl)*32 + dk) = o;
        } else {
          const size_t addr = (size_t)(b*8 + h)*65536
              + (size_t)(nl >> 5)*1024 + (size_t)((dk >> 4) & 1)*512
              + (size_t)((nl & 31) + 32*((dk >> 3) & 1))*8 + (dk & 7);
          *(u16x4*)(Ko + addr) = o;
        }
      }
    }
  } else {
#pragma unroll
    for (int ks = 0; ks < 8; ks++) {
      bf16x8 af[4], bfr[4];
#pragma unroll
      for (int nm = 0; nm < 4; nm++)
        af[nm] = load_cvt8(x + (size_t)(n0 + nm*16 + li)*256 + ks*32 + qt*8);
#pragma unroll
      for (int df = 0; df < 4; df++)
        bfr[df] = load_cvt8(wv + (size_t)(wave*64 + df*16 + li)*256 + ks*32 + qt*8);
#pragma unroll
      for (int nm = 0; nm < 4; nm++)
#pragma unroll
        for (int df = 0; df < 4; df++)
          acc[nm][df] = __builtin_amdgcn_mfma_f32_16x16x32_bf16(af[nm], bfr[df], acc[nm][df], 0, 0, 0);
    }
#pragma unroll
    for (int nm = 0; nm < 4; nm++) {
      const int nl = nl0 + nm*16 + qt*4;
#pragma unroll
      for (int df = 0; df < 4; df++) {
        const int d = wave*64 + df*16 + li;
        const int h = d >> 5, dv = d & 31;
        u16x4 o;
#pragma unroll
        for (int r = 0; r < 4; r++) o[r] = f2bf(acc[nm][df][r]);
        const size_t addr = (size_t)(b*8 + h)*65536
            + (size_t)(nl >> 5)*1024 + (size_t)((nl >> 4) & 1)*512
            + (size_t)(((nl >> 3) & 1)*32 + dv)*8 + (nl & 7);
        *(u16x4*)(Vto + addr) = o;
      }
    }
  }
}

// ---------------------------------------------------------------------------
// Kernel 2: fused flash attention + output projection — BARRIER-FREE main
// loop. The MFMA C-operand (edge/mask in exp2 domain) is built per-group
// directly from global memory: lane (ql,hi) reads f32x4/i32x4 chunks of its
// own q-row (k = KB*32 + rg*8 + hi*4 + r) — per-lane contiguous, L1-resident
// (32 KB/phase working set, shared by all 8 waves). No me LDS, no staging,
// no __syncthreads until the epilogue. Waves run their 64 K-tiles fully
// asynchronously (self-staggering latency hiding). K/V fragment-coalesced
// loads, streaming softmax, cvt_pk+permlane PV, split oacc, woF epilogue
// carried verbatim from R15.
// ---------------------------------------------------------------------------
__global__ __launch_bounds__(512, 2) void attn_kernel(
    const unsigned short* __restrict__ Qg,   // [B][H][N][32] linear
    const unsigned short* __restrict__ Kf,   // fragment order, 65536/head
    const unsigned short* __restrict__ Vf,   // fragment order, 65536/head
    const float* __restrict__ edge,          // [B][N][N]
    const int*   __restrict__ mask,          // [B][N][N]
    const unsigned short* __restrict__ woF,  // fragment order, 65536
    const float* __restrict__ bo,            // [256] f32
    float* __restrict__ Y)                   // [B*N][256] f32 (d_out)
{
  __shared__ __attribute__((aligned(16))) unsigned short o_lds[32][264]; // O tile

  const int bid = blockIdx.x;
  const int b  = (bid >> 1) & 3;                  // XCD pair per batch
  const int qi = ((bid >> 3) << 1) | (bid & 1);   // 0..63
  const int q0 = qi * 32;
  const int tid  = threadIdx.x;
  const int wave = tid >> 6;                 // = head
  const int lane = tid & 63;
  const int ql = lane & 31, hi = lane >> 5;
  const int h = wave;

  const unsigned short* qbase = Qg + ((size_t)(b*8 + h)*2048 + q0)*32;
  const unsigned short* kf = Kf + (size_t)(b*8 + h)*65536 + lane*8;
  const unsigned short* vf = Vf + (size_t)(b*8 + h)*65536 + lane*8;
  // per-lane edge/mask row pointers (k offset hi*4 baked in)
  const float* erow = edge + ((size_t)b*2048 + q0 + ql)*2048 + hi*4;
  const int*   mrow = mask + ((size_t)b*2048 + q0 + ql)*2048 + hi*4;

  // Q B-fragments
  const bf16x8 qf0 = *(const bf16x8*)(qbase + (size_t)ql*32 +  0 + hi*8);
  const bf16x8 qf1 = *(const bf16x8*)(qbase + (size_t)ql*32 + 16 + hi*8);

  // preload K tile 0 (fragment layout: lane*16B coalesced)
  bf16x8 kXa = *(const bf16x8*)(kf);
  bf16x8 kXb = *(const bf16x8*)(kf + 512);
  bf16x8 kYa, kYb;

  float lsum = 0.f;
  f32x16 oacc0 = (f32x16)0.0f;   // split PV accumulators
  f32x16 oacc1 = (f32x16)0.0f;

  union CU { f32x16 v; f32x4 q[4]; };

#define PV_KS(SV, HALF, VA, OA)                                               \
  {                                                                           \
    unsigned a0 = cvtpk(SV[(HALF)*8+0], SV[(HALF)*8+1]);                      \
    unsigned a1 = cvtpk(SV[(HALF)*8+2], SV[(HALF)*8+3]);                      \
    unsigned b0 = cvtpk(SV[(HALF)*8+4], SV[(HALF)*8+5]);                      \
    unsigned b1 = cvtpk(SV[(HALF)*8+6], SV[(HALF)*8+7]);                      \
    u32x2 p0 = __builtin_amdgcn_permlane32_swap(a0, b0, false, false);        \
    u32x2 p1 = __builtin_amdgcn_permlane32_swap(a1, b1, false, false);        \
    i32x4 pw4;                                                                \
    pw4[0] = (int)p0[0]; pw4[1] = (int)p1[0];                                 \
    pw4[2] = (int)p0[1]; pw4[3] = (int)p1[1];                                 \
    const bf16x8 pf = __builtin_bit_cast(bf16x8, pw4);                        \
    OA = __builtin_amdgcn_mfma_f32_32x32x16_bf16(VA, pf, OA, 0, 0, 0);        \
  }

  // One 32-key tile KB: prefetch K(KB+1); C-in built from global edge/mask.
  // C layout (32x32x16): col = q = ql, row = k = (r&3) + 8*rg + 4*hi.
#define GROUP(KB, KCa, KCb, KNa, KNb)                                         \
  {                                                                           \
    const int nxt = (((KB) + 1) & 63) * 1024;                                 \
    KNa = *(const bf16x8*)(kf + nxt);                                         \
    KNb = *(const bf16x8*)(kf + nxt + 512);                                   \
    const bf16x8 vA0 = *(const bf16x8*)(vf + (KB)*1024);                      \
    const bf16x8 vA1 = *(const bf16x8*)(vf + (KB)*1024 + 512);                \
    CU c;                                                                     \
    _Pragma("unroll")                                                         \
    for (int rg = 0; rg < 4; rg++) {                                          \
      const f32x4 e = *(const f32x4*)(erow + (KB)*32 + rg*8);                 \
      const i32x4 m = *(const i32x4*)(mrow + (KB)*32 + rg*8);                 \
      _Pragma("unroll")                                                       \
      for (int r = 0; r < 4; r++)                                             \
        c.q[rg][r] = m[r] ? e[r]*LOG2E : NEGBIG;                              \
    }                                                                         \
    f32x16 s = __builtin_amdgcn_mfma_f32_32x32x16_bf16(KCa, qf0, c.v, 0, 0, 0); \
    s = __builtin_amdgcn_mfma_f32_32x32x16_bf16(KCb, qf1, s, 0, 0, 0);        \
    _Pragma("unroll")                                                         \
    for (int i = 0; i < 16; i++) s[i] = __builtin_amdgcn_exp2f(s[i]);         \
    {                                                                         \
      float r0 = 0.f, r1 = 0.f, r2 = 0.f, r3 = 0.f;                           \
      _Pragma("unroll")                                                       \
      for (int i = 0; i < 4; i++) {                                           \
        r0 += s[4*i]; r1 += s[4*i+1]; r2 += s[4*i+2]; r3 += s[4*i+3];         \
      }                                                                       \
      lsum += (r0 + r1) + (r2 + r3);                                          \
    }                                                                         \
    PV_KS(s, 0, vA0, oacc0)                                                   \
    PV_KS(s, 1, vA1, oacc1)                                                   \
  }

  // barrier-free main loop: 64 tiles, 4 per iteration (scheduling window)
  for (int t = 0; t < 64; t += 4) {
    GROUP(t,     kXa, kXb, kYa, kYb)
    GROUP(t + 1, kYa, kYb, kXa, kXb)
    GROUP(t + 2, kXa, kXb, kYa, kYb)
    GROUP(t + 3, kYa, kYb, kXa, kXb)
  }
#undef GROUP
#undef PV_KS

  // ---- epilogue 1: merge accumulators, normalize, stage O tile in LDS ----
  {
    const f32x16 oacc = oacc0 + oacc1;
    const float ltot = lsum + __shfl_xor(lsum, 32);
    const float rl = 1.0f / ltot;
#pragma unroll
    for (int rg = 0; rg < 4; rg++) {
      u16x4 o;
#pragma unroll
      for (int r = 0; r < 4; r++) o[r] = f2bf(oacc[rg*4 + r] * rl);
      *(u16x4*)&o_lds[ql][h*32 + rg*8 + hi*4] = o;
    }
  }
  __syncthreads();

  // ---- epilogue 2: y(32n x 256d) = O @ wo^T + bo; wave = dout slice ----
  {
    const int li = lane & 15, qt = lane >> 4;
    const unsigned short* wof = woF + wave*8192 + lane*8;
    f32x4 acc2[2][2];
#pragma unroll
    for (int i = 0; i < 2; i++)
#pragma unroll
      for (int j = 0; j < 2; j++) acc2[i][j] = (f32x4)0.0f;
#pragma unroll
    for (int ks = 0; ks < 8; ks++) {
      const bf16x8 af0 = *(const bf16x8*)(wof + ks*1024);
      const bf16x8 af1 = *(const bf16x8*)(wof + ks*1024 + 512);
      const bf16x8 b0 = *(const bf16x8*)&o_lds[li][ks*32 + qt*8];
      const bf16x8 b1 = *(const bf16x8*)&o_lds[16 + li][ks*32 + qt*8];
      acc2[0][0] = __builtin_amdgcn_mfma_f32_16x16x32_bf16(af0, b0, acc2[0][0], 0, 0, 0);
      acc2[0][1] = __builtin_amdgcn_mfma_f32_16x16x32_bf16(af0, b1, acc2[0][1], 0, 0, 0);
      acc2[1][0] = __builtin_amdgcn_mfma_f32_16x16x32_bf16(af1, b0, acc2[1][0], 0, 0, 0);
      acc2[1][1] = __builtin_amdgcn_mfma_f32_16x16x32_bf16(af1, b1, acc2[1][1], 0, 0, 0);
    }
    // C^T: row = dout = wave*32 + df*16 + qt*4 + r ; col = n = nf*16 + li
#pragma unroll
    for (int df = 0; df < 2; df++) {
      const int d0 = wave*32 + df*16 + qt*4;
      const f32x4 bo4 = *(const f32x4*)(bo + d0);
#pragma unroll
      for (int nf = 0; nf < 2; nf++) {
        const int n = nf*16 + li;
        f32x4 y = acc2[df][nf] + bo4;
        *(f32x4*)(Y + ((size_t)(b*2048 + q0 + n))*256 + d0) = y;
      }
    }
  }
}

// ---------------------------------------------------------------------------
extern "C" void kernel_launch(void* const* d_in, const int* in_sizes, int n_in,
                              void* d_out, int out_size, void* d_ws, size_t ws_size,
                              hipStream_t stream) {
  const float* x  = (const float*)d_in[0];
  const float* ew = (const float*)d_in[1];
  const int*   mk = (const int*)d_in[2];
  const float* wq = (const float*)d_in[3];
  const float* wk = (const float*)d_in[4];
  const float* wv = (const float*)d_in[5];
  const float* wo = (const float*)d_in[6];
  const float* bo = (const float*)d_in[7];
  float* y = (float*)d_out;

  unsigned short* Q   = (unsigned short*)d_ws;      // [4][8][2048][32] bf16
  unsigned short* Kf  = Q  + 2097152;               // fragment order
  unsigned short* Vf  = Kf + 2097152;               // fragment order
  unsigned short* woF = Vf + 2097152;               // wo fragment order, 65536

  qkv_kernel<<<dim3(128, 4), 256, 0, stream>>>(x, wq, wk, wv, wo, Q, Kf, Vf, woF);
  attn_kernel<<<256, 512, 0, stream>>>(Q, Kf, Vf, ew, mk, woF, bo, y);
}

// Round 17
// 80.869 us; speedup vs baseline: 2.1556x; 2.1556x over previous
//
#include <hip/hip_runtime.h>

#define LOG2E 1.4426950408889634f
#define NEGBIG -3.0e38f

typedef float  f32x4  __attribute__((ext_vector_type(4)));
typedef float  f32x16 __attribute__((ext_vector_type(16)));
typedef short  bf16x8 __attribute__((ext_vector_type(8)));
typedef unsigned short u16x4 __attribute__((ext_vector_type(4)));
typedef int    i32x4  __attribute__((ext_vector_type(4)));
typedef unsigned int u32x2 __attribute__((ext_vector_type(2)));

__device__ __forceinline__ unsigned short f2bf(float f) {
  union { float f; unsigned u; } v; v.f = f;
  unsigned r = v.u + 0x7FFFu + ((v.u >> 16) & 1u);
  return (unsigned short)(r >> 16);
}

__device__ __forceinline__ unsigned cvtpk(float a, float b) {
  unsigned r;
  asm("v_cvt_pk_bf16_f32 %0, %1, %2" : "=v"(r) : "v"(a), "v"(b));
  return r;
}

__device__ __forceinline__ bf16x8 load_cvt8(const float* p) {
  f32x4 a = *(const f32x4*)p;
  f32x4 b = *(const f32x4*)(p + 4);
  bf16x8 r;
  r[0]=(short)f2bf(a[0]); r[1]=(short)f2bf(a[1]); r[2]=(short)f2bf(a[2]); r[3]=(short)f2bf(a[3]);
  r[4]=(short)f2bf(b[0]); r[5]=(short)f2bf(b[1]); r[6]=(short)f2bf(b[2]); r[7]=(short)f2bf(b[3]);
  return r;
}

// ---------------------------------------------------------------------------
// Kernel 1: QKV projection + weight repack (R15 version, known-good).
// mode 0: Q linear; mode 1: K fragment order; mode 2: V fragment order;
// mode 3: wo -> woF bf16 fragment order.
// ---------------------------------------------------------------------------
__global__ __launch_bounds__(256) void qkv_kernel(
    const float* __restrict__ x,
    const float* __restrict__ wq, const float* __restrict__ wk, const float* __restrict__ wv,
    const float* __restrict__ wo,
    unsigned short* __restrict__ Qo, unsigned short* __restrict__ Ko,
    unsigned short* __restrict__ Vto, unsigned short* __restrict__ woF)
{
  const int mode = blockIdx.y;
  if (mode == 3) {
    const int e = (blockIdx.x*256 + threadIdx.x) * 2;   // 0..65534, even
    const int wv_ = e >> 13;
    const int ks  = (e >> 10) & 7;
    const int df  = (e >> 9) & 1;
    const int lp  = (e >> 3) & 63;
    const int j   = e & 7;
    const int row = wv_*32 + df*16 + (lp & 15);
    const int col = ks*32 + (lp >> 4)*8 + j;
    const float a0 = wo[(size_t)row*256 + col];
    const float a1 = wo[(size_t)row*256 + col + 1];
    woF[e]     = f2bf(a0);
    woF[e + 1] = f2bf(a1);
    return;
  }
  const int n0   = blockIdx.x * 64;
  const int b    = n0 >> 11;
  const int nl0  = n0 & 2047;
  const int wave = threadIdx.x >> 6;
  const int lane = threadIdx.x & 63;
  const int li = lane & 15, qt = lane >> 4;

  f32x4 acc[4][4];
#pragma unroll
  for (int i = 0; i < 4; i++)
#pragma unroll
    for (int j = 0; j < 4; j++) acc[i][j] = (f32x4)0.0f;

  if (mode < 2) {
    const float* w = mode ? wk : wq;
    const float osc = mode ? 1.0f : (1.4426950408889634f / 5.656854249492381f);
#pragma unroll
    for (int ks = 0; ks < 8; ks++) {
      bf16x8 af[4], bfr[4];
#pragma unroll
      for (int dm = 0; dm < 4; dm++)
        af[dm] = load_cvt8(w + (size_t)(wave*64 + dm*16 + li)*256 + ks*32 + qt*8);
#pragma unroll
      for (int nf = 0; nf < 4; nf++)
        bfr[nf] = load_cvt8(x + (size_t)(n0 + nf*16 + li)*256 + ks*32 + qt*8);
#pragma unroll
      for (int dm = 0; dm < 4; dm++)
#pragma unroll
        for (int nf = 0; nf < 4; nf++)
          acc[dm][nf] = __builtin_amdgcn_mfma_f32_16x16x32_bf16(af[dm], bfr[nf], acc[dm][nf], 0, 0, 0);
    }
#pragma unroll
    for (int dm = 0; dm < 4; dm++) {
      const int dbase = wave*64 + dm*16 + qt*4;
      const int h = dbase >> 5, dk = dbase & 31;
#pragma unroll
      for (int nf = 0; nf < 4; nf++) {
        const int nl = nl0 + nf*16 + li;
        u16x4 o;
#pragma unroll
        for (int r = 0; r < 4; r++) o[r] = f2bf(acc[dm][nf][r] * osc);
        if (mode == 0) {
          *(u16x4*)(Qo + ((size_t)(b*8 + h)*2048 + nl)*32 + dk) = o;
        } else {
          const size_t addr = (size_t)(b*8 + h)*65536
              + (size_t)(nl >> 5)*1024 + (size_t)((dk >> 4) & 1)*512
              + (size_t)((nl & 31) + 32*((dk >> 3) & 1))*8 + (dk & 7);
          *(u16x4*)(Ko + addr) = o;
        }
      }
    }
  } else {
#pragma unroll
    for (int ks = 0; ks < 8; ks++) {
      bf16x8 af[4], bfr[4];
#pragma unroll
      for (int nm = 0; nm < 4; nm++)
        af[nm] = load_cvt8(x + (size_t)(n0 + nm*16 + li)*256 + ks*32 + qt*8);
#pragma unroll
      for (int df = 0; df < 4; df++)
        bfr[df] = load_cvt8(wv + (size_t)(wave*64 + df*16 + li)*256 + ks*32 + qt*8);
#pragma unroll
      for (int nm = 0; nm < 4; nm++)
#pragma unroll
        for (int df = 0; df < 4; df++)
          acc[nm][df] = __builtin_amdgcn_mfma_f32_16x16x32_bf16(af[nm], bfr[df], acc[nm][df], 0, 0, 0);
    }
#pragma unroll
    for (int nm = 0; nm < 4; nm++) {
      const int nl = nl0 + nm*16 + qt*4;
#pragma unroll
      for (int df = 0; df < 4; df++) {
        const int d = wave*64 + df*16 + li;
        const int h = d >> 5, dv = d & 31;
        u16x4 o;
#pragma unroll
        for (int r = 0; r < 4; r++) o[r] = f2bf(acc[nm][df][r]);
        const size_t addr = (size_t)(b*8 + h)*65536
            + (size_t)(nl >> 5)*1024 + (size_t)((nl >> 4) & 1)*512
            + (size_t)(((nl >> 3) & 1)*32 + dv)*8 + (nl & 7);
        *(u16x4*)(Vto + addr) = o;
      }
    }
  }
}

// ---------------------------------------------------------------------------
// Kernel 2: fused flash attention + output projection. R15 structure with
// 256-key phases: 8 barriers instead of 16 (me_s 2 x 32 KB, 4 staged chunks
// per thread, +32 staging VGPRs — safe under the (512,2) 256-VGPR cap, unlike
// R9's spill under (512,4)). Inner GROUP loop, fragment-coalesced Kf/Vf,
// streaming softmax, cvt_pk+permlane PV, split oacc, woF epilogue: R15
// verbatim. Sync = __syncthreads() only.
// ---------------------------------------------------------------------------
__global__ __launch_bounds__(512, 2) void attn_kernel(
    const unsigned short* __restrict__ Qg,   // [B][H][N][32] linear
    const unsigned short* __restrict__ Kf,   // fragment order, 65536/head
    const unsigned short* __restrict__ Vf,   // fragment order, 65536/head
    const float* __restrict__ edge,          // [B][N][N]
    const int*   __restrict__ mask,          // [B][N][N]
    const unsigned short* __restrict__ woF,  // fragment order, 65536
    const float* __restrict__ bo,            // [256] f32
    float* __restrict__ Y)                   // [B*N][256] f32 (d_out)
{
  __shared__ __attribute__((aligned(16))) float me_s[2][8192];  // 2 x (32q x 256k)
  __shared__ __attribute__((aligned(16))) unsigned short o_lds[32][264]; // O tile

  const int bid = blockIdx.x;
  const int b  = (bid >> 1) & 3;                  // XCD pair per batch
  const int qi = ((bid >> 3) << 1) | (bid & 1);   // 0..63
  const int q0 = qi * 32;
  const int tid  = threadIdx.x;
  const int wave = tid >> 6;                 // = head
  const int lane = tid & 63;
  const int ql = lane & 31, hi = lane >> 5;
  const int h = wave;

  const unsigned short* qbase = Qg + ((size_t)(b*8 + h)*2048 + q0)*32;
  const unsigned short* kf = Kf + (size_t)(b*8 + h)*65536 + lane*8;
  const unsigned short* vf = Vf + (size_t)(b*8 + h)*65536 + lane*8;

  // staging map: thread t -> (q = t>>4 in 0..31, keys (t&15)*4 + c*64, c=0..3)
  const int q_s = tid >> 4;
  const int k4  = (tid & 15) * 4;
  const float* eaddr = edge + ((size_t)b*2048 + q0 + q_s)*2048 + k4;
  const int*   maddr = mask + ((size_t)b*2048 + q0 + q_s)*2048 + k4;
  // me layout per 32-key tile T (1024 floats): quad (q, k4) ->
  //   C2 = ((k&31)>>3)*2 + ((k>>2)&1); idx = T*1024 + (C2*32 + (q^C2))*4 + (k&3)
  // chunk c (+64 keys) -> +2048 floats.
  const int sC2  = (((k4 & 31) >> 3) * 2) + ((k4 >> 2) & 1);
  const int widx = (k4 >> 5)*1024 + (sC2*32 + (q_s ^ sC2))*4;
  // C-in read float-offsets per rg (C2 = rg*2+hi); add T*1024 at use site
  int rix[4];
#pragma unroll
  for (int rg = 0; rg < 4; rg++) {
    const int C2 = rg*2 + hi;
    rix[rg] = (C2*32 + (ql ^ C2)) * 4;
  }

  // Q B-fragments
  const bf16x8 qf0 = *(const bf16x8*)(qbase + (size_t)ql*32 +  0 + hi*8);
  const bf16x8 qf1 = *(const bf16x8*)(qbase + (size_t)ql*32 + 16 + hi*8);

#define STAGE_WRITE(BUF, E0, M0, E1, M1, E2, M2, E3, M3)                      \
  {                                                                           \
    f32x4 w0, w1, w2, w3;                                                     \
    _Pragma("unroll")                                                         \
    for (int r = 0; r < 4; r++) {                                             \
      w0[r] = M0[r] ? E0[r]*LOG2E : NEGBIG;                                   \
      w1[r] = M1[r] ? E1[r]*LOG2E : NEGBIG;                                   \
      w2[r] = M2[r] ? E2[r]*LOG2E : NEGBIG;                                   \
      w3[r] = M3[r] ? E3[r]*LOG2E : NEGBIG;                                   \
    }                                                                         \
    *(f32x4*)&me_s[BUF][widx]        = w0;                                    \
    *(f32x4*)&me_s[BUF][widx + 2048] = w1;                                    \
    *(f32x4*)&me_s[BUF][widx + 4096] = w2;                                    \
    *(f32x4*)&me_s[BUF][widx + 6144] = w3;                                    \
  }

  { // stage phase 0 (keys 0..255)
    f32x4 e0 = *(const f32x4*)eaddr;         i32x4 m0 = *(const i32x4*)maddr;
    f32x4 e1 = *(const f32x4*)(eaddr + 64);  i32x4 m1 = *(const i32x4*)(maddr + 64);
    f32x4 e2 = *(const f32x4*)(eaddr + 128); i32x4 m2 = *(const i32x4*)(maddr + 128);
    f32x4 e3 = *(const f32x4*)(eaddr + 192); i32x4 m3 = *(const i32x4*)(maddr + 192);
    STAGE_WRITE(0, e0, m0, e1, m1, e2, m2, e3, m3)
  }
  __syncthreads();

  // issue phase-1 edge/mask loads
  f32x4 se0 = *(const f32x4*)(eaddr + 256);  i32x4 sm0 = *(const i32x4*)(maddr + 256);
  f32x4 se1 = *(const f32x4*)(eaddr + 320);  i32x4 sm1 = *(const i32x4*)(maddr + 320);
  f32x4 se2 = *(const f32x4*)(eaddr + 384);  i32x4 sm2 = *(const i32x4*)(maddr + 384);
  f32x4 se3 = *(const f32x4*)(eaddr + 448);  i32x4 sm3 = *(const i32x4*)(maddr + 448);

  // preload K tile 0 (fragment layout: lane*16B coalesced)
  bf16x8 kXa = *(const bf16x8*)(kf);
  bf16x8 kXb = *(const bf16x8*)(kf + 512);
  bf16x8 kYa, kYb;

  float lsum = 0.f;
  f32x16 oacc0 = (f32x16)0.0f;   // split PV accumulators
  f32x16 oacc1 = (f32x16)0.0f;

  union CU { f32x16 v; f32x4 q[4]; };

#define PV_KS(SV, HALF, VA, OA)                                               \
  {                                                                           \
    unsigned a0 = cvtpk(SV[(HALF)*8+0], SV[(HALF)*8+1]);                      \
    unsigned a1 = cvtpk(SV[(HALF)*8+2], SV[(HALF)*8+3]);                      \
    unsigned b0 = cvtpk(SV[(HALF)*8+4], SV[(HALF)*8+5]);                      \
    unsigned b1 = cvtpk(SV[(HALF)*8+6], SV[(HALF)*8+7]);                      \
    u32x2 p0 = __builtin_amdgcn_permlane32_swap(a0, b0, false, false);        \
    u32x2 p1 = __builtin_amdgcn_permlane32_swap(a1, b1, false, false);        \
    i32x4 pw4;                                                                \
    pw4[0] = (int)p0[0]; pw4[1] = (int)p1[0];                                 \
    pw4[2] = (int)p0[1]; pw4[3] = (int)p1[1];                                 \
    const bf16x8 pf = __builtin_bit_cast(bf16x8, pw4);                        \
    OA = __builtin_amdgcn_mfma_f32_32x32x16_bf16(VA, pf, OA, 0, 0, 0);        \
  }

  // One 32-key tile: prefetch K of tile KB+1, compute on current K regs.
#define GROUP(KB, T, KCa, KCb, KNa, KNb)                                      \
  {                                                                           \
    const size_t nxt = (size_t)(((KB) + 1) & 63) * 1024;                      \
    KNa = *(const bf16x8*)(kf + nxt);                                         \
    KNb = *(const bf16x8*)(kf + nxt + 512);                                   \
    const bf16x8 vA0 = *(const bf16x8*)(vf + (size_t)(KB)*1024);              \
    const bf16x8 vA1 = *(const bf16x8*)(vf + (size_t)(KB)*1024 + 512);        \
    CU c;                                                                     \
    _Pragma("unroll")                                                         \
    for (int rg = 0; rg < 4; rg++)                                            \
      c.q[rg] = *(const f32x4*)(mb + (T)*1024 + rix[rg]);                     \
    f32x16 s = __builtin_amdgcn_mfma_f32_32x32x16_bf16(KCa, qf0, c.v, 0, 0, 0); \
    s = __builtin_amdgcn_mfma_f32_32x32x16_bf16(KCb, qf1, s, 0, 0, 0);        \
    _Pragma("unroll")                                                         \
    for (int i = 0; i < 16; i++) s[i] = __builtin_amdgcn_exp2f(s[i]);         \
    {                                                                         \
      float r0 = 0.f, r1 = 0.f, r2 = 0.f, r3 = 0.f;                           \
      _Pragma("unroll")                                                       \
      for (int i = 0; i < 4; i++) {                                           \
        r0 += s[4*i]; r1 += s[4*i+1]; r2 += s[4*i+2]; r3 += s[4*i+3];         \
      }                                                                       \
      lsum += (r0 + r1) + (r2 + r3);                                          \
    }                                                                         \
    PV_KS(s, 0, vA0, oacc0)                                                   \
    PV_KS(s, 1, vA1, oacc1)                                                   \
  }

  for (int p = 0; p < 8; ++p) {
    const float* mb = &me_s[p & 1][0];
    // write NEXT phase's buffer (data loaded 1 phase ago)
    if (p < 7) {
      STAGE_WRITE((p + 1) & 1, se0, sm0, se1, sm1, se2, sm2, se3, sm3)
    }
    if (p < 6) { // issue loads for phase p+2
      const int ofs = (p + 2)*256;
      se0 = *(const f32x4*)(eaddr + ofs);        sm0 = *(const i32x4*)(maddr + ofs);
      se1 = *(const f32x4*)(eaddr + ofs + 64);   sm1 = *(const i32x4*)(maddr + ofs + 64);
      se2 = *(const f32x4*)(eaddr + ofs + 128);  sm2 = *(const i32x4*)(maddr + ofs + 128);
      se3 = *(const f32x4*)(eaddr + ofs + 192);  sm3 = *(const i32x4*)(maddr + ofs + 192);
    }
    const int g0 = p * 8;
    GROUP(g0,     0, kXa, kXb, kYa, kYb)
    GROUP(g0 + 1, 1, kYa, kYb, kXa, kXb)
    GROUP(g0 + 2, 2, kXa, kXb, kYa, kYb)
    GROUP(g0 + 3, 3, kYa, kYb, kXa, kXb)
    GROUP(g0 + 4, 4, kXa, kXb, kYa, kYb)
    GROUP(g0 + 5, 5, kYa, kYb, kXa, kXb)
    GROUP(g0 + 6, 6, kXa, kXb, kYa, kYb)
    GROUP(g0 + 7, 7, kYa, kYb, kXa, kXb)
    __syncthreads();
  }
#undef GROUP
#undef PV_KS
#undef STAGE_WRITE

  // ---- epilogue 1: merge accumulators, normalize, stage O tile in LDS ----
  {
    const f32x16 oacc = oacc0 + oacc1;
    const float ltot = lsum + __shfl_xor(lsum, 32);
    const float rl = 1.0f / ltot;
#pragma unroll
    for (int rg = 0; rg < 4; rg++) {
      u16x4 o;
#pragma unroll
      for (int r = 0; r < 4; r++) o[r] = f2bf(oacc[rg*4 + r] * rl);
      *(u16x4*)&o_lds[ql][h*32 + rg*8 + hi*4] = o;
    }
  }
  __syncthreads();

  // ---- epilogue 2: y(32n x 256d) = O @ wo^T + bo; wave = dout slice ----
  {
    const int li = lane & 15, qt = lane >> 4;
    const unsigned short* wof = woF + wave*8192 + lane*8;
    f32x4 acc2[2][2];
#pragma unroll
    for (int i = 0; i < 2; i++)
#pragma unroll
      for (int j = 0; j < 2; j++) acc2[i][j] = (f32x4)0.0f;
#pragma unroll
    for (int ks = 0; ks < 8; ks++) {
      const bf16x8 af0 = *(const bf16x8*)(wof + ks*1024);
      const bf16x8 af1 = *(const bf16x8*)(wof + ks*1024 + 512);
      const bf16x8 b0 = *(const bf16x8*)&o_lds[li][ks*32 + qt*8];
      const bf16x8 b1 = *(const bf16x8*)&o_lds[16 + li][ks*32 + qt*8];
      acc2[0][0] = __builtin_amdgcn_mfma_f32_16x16x32_bf16(af0, b0, acc2[0][0], 0, 0, 0);
      acc2[0][1] = __builtin_amdgcn_mfma_f32_16x16x32_bf16(af0, b1, acc2[0][1], 0, 0, 0);
      acc2[1][0] = __builtin_amdgcn_mfma_f32_16x16x32_bf16(af1, b0, acc2[1][0], 0, 0, 0);
      acc2[1][1] = __builtin_amdgcn_mfma_f32_16x16x32_bf16(af1, b1, acc2[1][1], 0, 0, 0);
    }
    // C^T: row = dout = wave*32 + df*16 + qt*4 + r ; col = n = nf*16 + li
#pragma unroll
    for (int df = 0; df < 2; df++) {
      const int d0 = wave*32 + df*16 + qt*4;
      const f32x4 bo4 = *(const f32x4*)(bo + d0);
#pragma unroll
      for (int nf = 0; nf < 2; nf++) {
        const int n = nf*16 + li;
        f32x4 y = acc2[df][nf] + bo4;
        *(f32x4*)(Y + ((size_t)(b*2048 + q0 + n))*256 + d0) = y;
      }
    }
  }
}

// ---------------------------------------------------------------------------
extern "C" void kernel_launch(void* const* d_in, const int* in_sizes, int n_in,
                              void* d_out, int out_size, void* d_ws, size_t ws_size,
                              hipStream_t stream) {
  const float* x  = (const float*)d_in[0];
  const float* ew = (const float*)d_in[1];
  const int*   mk = (const int*)d_in[2];
  const float* wq = (const float*)d_in[3];
  const float* wk = (const float*)d_in[4];
  const float* wv = (const float*)d_in[5];
  const float* wo = (const float*)d_in[6];
  const float* bo = (const float*)d_in[7];
  float* y = (float*)d_out;

  unsigned short* Q   = (unsigned short*)d_ws;      // [4][8][2048][32] bf16
  unsigned short* Kf  = Q  + 2097152;               // fragment order
  unsigned short* Vf  = Kf + 2097152;               // fragment order
  unsigned short* woF = Vf + 2097152;               // wo fragment order, 65536

  qkv_kernel<<<dim3(128, 4), 256, 0, stream>>>(x, wq, wk, wv, wo, Q, Kf, Vf, woF);
  attn_kernel<<<256, 512, 0, stream>>>(Q, Kf, Vf, ew, mk, woF, bo, y);
}